// Round 9
// baseline (165.312 us; speedup 1.0000x reference)
//
#include <hip/hip_runtime.h>
#include <hip/hip_bf16.h>

typedef __attribute__((ext_vector_type(8))) short  s16x8;   // 8 x bf16
typedef __attribute__((ext_vector_type(4))) short  s16x4;
typedef __attribute__((ext_vector_type(4))) float  f32x4;

#define T_LEN 50000
#define S_LEN 168
#define W_IN  336
#define O_OUT 48
#define N_ROWS (T_LEN - W_IN - O_OUT + 1)   // 49617
#define N_PAD  49664                        // 776 * 64
#define NBLK   (N_PAD / 64)                 // 776

__device__ inline short f2bf(float f) {
    union { float f; unsigned u; } v; v.f = f;
    unsigned u = v.u;
    unsigned r = u + 0x7fffu + ((u >> 16) & 1u);   // RNE
    return (short)(r >> 16);
}

__device__ inline int bfpk(float lo, float hi) {   // 2xf32 -> packed 2xbf16 (RNE)
    float2 f2; f2.x = lo; f2.y = hi;
    __hip_bfloat162 h = __float22bfloat162_rn(f2);
    int r; __builtin_memcpy(&r, &h, 4);
    return r;
}

__device__ inline float readlane_f(float v, int l) {
    return __int_as_float(__builtin_amdgcn_readlane(__float_as_int(v), l));
}

__device__ inline float fast_tanh(float v) {
    float e = __expf(2.f * v);
    return 1.f - 2.f * __builtin_amdgcn_rcpf(e + 1.f);
}

// ---------------- pre-convert W1 -> W1T bf16 [352][352] (zero-padded), W2 -> W2T [48][360] --
__global__ void k_preconvert(const float* __restrict__ W1, const float* __restrict__ W2,
                             short* __restrict__ W1T, short* __restrict__ W2T) {
    int idx = blockIdx.x * 256 + threadIdx.x;
    const int n1 = 352 * 352;
    const int tot = n1 + 48 * 360;
    if (idx >= tot) return;
    if (idx < n1) {
        int j = idx / 352, k = idx % 352;
        W1T[idx] = (j < 336 && k < 336) ? f2bf(W1[k * 336 + j]) : (short)0;
    } else {
        int i2 = idx - n1;
        int o = i2 / 360, k = i2 % 360;
        W2T[i2] = (k < 336) ? f2bf(W2[k * 48 + o]) : (short)0;
    }
}

// ---------------- scan: packed lw stores, row_bcast DPP scan, peeled clamp -----------------
// DPP_FMA: q += W * dpp(q); excluded rows (row_mask) contribute 0 (old=0).
#define DPP_FMA(q_, CTRL, W, RM) { \
    int t_ = __builtin_amdgcn_update_dpp(0, __float_as_int(q_), (CTRL), (RM), 0xf, true); \
    q_ = fmaf((W), __int_as_float(t_), q_); }

__global__ void k_scan(const float* __restrict__ x, const float* __restrict__ level_sc,
                       const float* __restrict__ seas_sc, const float* __restrict__ init_seas,
                       float* __restrict__ lw, float* __restrict__ seasinit) {
    __shared__ float ring[256];      // ring[s & 255] = seas(s)
    int lane = threadIdx.x;          // 64 threads, 1 wave
    float a = 1.f / (1.f + expf(-level_sc[0]));
    float g = 1.f / (1.f + expf(-seas_sc[0]));
    float om = 1.f - a, omg = 1.f - g;

    for (int t = lane; t < 256; t += 64) {
        float s = 1.f;
        if (t <= S_LEN) { s = expf(init_seas[t < S_LEN ? t : 0]); seasinit[t] = s; }
        ring[t] = s;
    }
    float lpv = x[0] / expf(init_seas[0]);
    if (lane == 0) { lw[0] = lpv; lw[1] = 1.f; }
    __syncthreads();

    float om1 = om, om2v = om1 * om1, om4 = om2v * om2v, om8 = om4 * om4;
    float pl    = powf(om, (float)(lane + 1));
    float fpre  = powf(om, (float)((lane & 15) + 1));
    float fpre2 = powf(om, (float)((lane & 31) + 1));

    // weighted inclusive scan over 64 lanes:
    // 4 intra-row shifts, then row_bcast15 (rows 1,3: prev-row tail) + row_bcast31 (rows 2,3: Q31)
#define SCAN(QOUT, XV, RSV) { \
    float q_ = a * (XV) * (RSV); \
    DPP_FMA(q_, 0x111, om1,  0xf); \
    DPP_FMA(q_, 0x112, om2v, 0xf); \
    DPP_FMA(q_, 0x114, om4,  0xf); \
    DPP_FMA(q_, 0x118, om8,  0xf); \
    DPP_FMA(q_, 0x142, fpre,  0xa); \
    DPP_FMA(q_, 0x143, fpre2, 0xc); \
    QOUT = q_; }

#define XLOAD(I) float xr##I = x[1 + 64 * I + lane];
    XLOAD(0) XLOAD(1) XLOAD(2) XLOAD(3) XLOAD(4) XLOAD(5) XLOAD(6) XLOAD(7)
    XLOAD(8) XLOAD(9) XLOAD(10) XLOAD(11) XLOAD(12) XLOAD(13) XLOAD(14) XLOAD(15)
#undef XLOAD

    // prologue: seas chunk 0; scan chunk 0; issue read for chunk 1
    float sA0 = ring[1 + lane];
    float Qcur; SCAN(Qcur, xr0, __builtin_amdgcn_rcpf(sA0));
    float sW = sA0;
    float ldsA = ring[65 + lane];
    float ldsB;
    int ib = 1;

#define BODY(R, RN, LIN, LOUT, CLAMP) { \
    float lvl = fmaf(pl, lpv, Qcur); \
    lpv = readlane_f(lvl, 63); \
    float w_ = fmaf(omg, sW, (g * xr##R) * __builtin_amdgcn_rcpf(lvl)); \
    float2 pk_; pk_.x = lvl; pk_.y = w_; \
    *(float2*)&lw[2 * (ib + lane)] = pk_; \
    ring[(ib + S_LEN + lane) & 255] = w_; \
    LOUT = ring[(ib + 128 + lane) & 255]; \
    float Qn_; SCAN(Qn_, xr##RN, __builtin_amdgcn_rcpf(LIN)); \
    int pidx = ib + 1024 + lane; \
    if (CLAMP) pidx = pidx > (T_LEN - 1) ? (T_LEN - 1) : pidx; \
    xr##R = x[pidx]; \
    Qcur = Qn_; sW = LIN; \
    ib += 64; }

    for (int kb = 0; kb < 47; ++kb) {   // 47*16 = 752 unclamped iters
        BODY(0,1,  ldsA, ldsB, 0) BODY(1,2,  ldsB, ldsA, 0) BODY(2,3,  ldsA, ldsB, 0) BODY(3,4,  ldsB, ldsA, 0)
        BODY(4,5,  ldsA, ldsB, 0) BODY(5,6,  ldsB, ldsA, 0) BODY(6,7,  ldsA, ldsB, 0) BODY(7,8,  ldsB, ldsA, 0)
        BODY(8,9,  ldsA, ldsB, 0) BODY(9,10, ldsB, ldsA, 0) BODY(10,11,ldsA, ldsB, 0) BODY(11,12,ldsB, ldsA, 0)
        BODY(12,13,ldsA, ldsB, 0) BODY(13,14,ldsB, ldsA, 0) BODY(14,15,ldsA, ldsB, 0) BODY(15,0, ldsB, ldsA, 0)
    }
    // 13 unclamped: k = 752..764 (slots 0..12)
    BODY(0,1,  ldsA, ldsB, 0) BODY(1,2,  ldsB, ldsA, 0) BODY(2,3,  ldsA, ldsB, 0) BODY(3,4,  ldsB, ldsA, 0)
    BODY(4,5,  ldsA, ldsB, 0) BODY(5,6,  ldsB, ldsA, 0) BODY(6,7,  ldsA, ldsB, 0) BODY(7,8,  ldsB, ldsA, 0)
    BODY(8,9,  ldsA, ldsB, 0) BODY(9,10, ldsB, ldsA, 0) BODY(10,11,ldsA, ldsB, 0) BODY(11,12,ldsB, ldsA, 0)
    BODY(12,13,ldsA, ldsB, 0)
    // 15 clamped: k = 765..779 (slots 13,14,15,0..11)
    BODY(13,14,ldsB, ldsA, 1) BODY(14,15,ldsA, ldsB, 1) BODY(15,0, ldsB, ldsA, 1)
    BODY(0,1,  ldsA, ldsB, 1) BODY(1,2,  ldsB, ldsA, 1) BODY(2,3,  ldsA, ldsB, 1) BODY(3,4,  ldsB, ldsA, 1)
    BODY(4,5,  ldsA, ldsB, 1) BODY(5,6,  ldsB, ldsA, 1) BODY(6,7,  ldsA, ldsB, 1) BODY(7,8,  ldsB, ldsA, 1)
    BODY(8,9,  ldsA, ldsB, 1) BODY(9,10, ldsB, ldsA, 1) BODY(10,11,ldsA, ldsB, 1) BODY(11,12,ldsB, ldsA, 1)
#undef BODY

    {   // propagate chunk 780 (steps 49921..49984; sW = seas(780), Qcur = Q(780))
        float lvl = fmaf(pl, lpv, Qcur);
        lpv = readlane_f(lvl, 63);
        float w_ = fmaf(omg, sW, (g * xr12) * __builtin_amdgcn_rcpf(lvl));
        float2 pk_; pk_.x = lvl; pk_.y = w_;
        *(float2*)&lw[2 * (49921 + lane)] = pk_;
    }
    {   // chunk 781 (steps 49985..49999, lanes 0..14; ldsA = seas(781) pending)
        float Qn_; SCAN(Qn_, xr13, __builtin_amdgcn_rcpf(ldsA));
        float lvl = fmaf(pl, lpv, Qn_);
        if (lane < 15) {
            float w_ = fmaf(omg, ldsA, (g * xr13) * __builtin_amdgcn_rcpf(lvl));
            float2 pk_; pk_.x = lvl; pk_.y = w_;
            *(float2*)&lw[2 * (49985 + lane)] = pk_;
        }
    }
#undef SCAN
}

// ---------------- logs + loss partials: F, llev from packed lw ------------------------------
__global__ void k_logs(const float* __restrict__ x, const float* __restrict__ lw,
                       const float* __restrict__ seasinit,
                       float* __restrict__ F, float* __restrict__ llev,
                       float* __restrict__ partials) {
    __shared__ float sm[258];
    __shared__ float red[256];
    int tid = threadIdx.x;
    int t = blockIdx.x * 256 + tid;
    float ll = 0.f;
    if (t < T_LEN) {
        float2 cur = *(const float2*)&lw[2 * t];
        int ps = t - S_LEN; if (ps < 0) ps = 0;
        float sv = (t <= S_LEN) ? seasinit[t] : lw[2 * ps + 1];
        F[t]  = __logf(x[t]) - __logf(sv);
        ll    = __logf(cur.x);
        llev[t] = ll;
    }
    sm[tid] = ll;
    if (tid < 2) {
        int te = blockIdx.x * 256 + 256 + tid;
        sm[256 + tid] = (te < T_LEN) ? __logf(lw[2 * te]) : 0.f;
    }
    __syncthreads();
    float s = 0.f;
    if (t < T_LEN - 2) {
        float d = sm[tid + 2] - 2.f * sm[tid + 1] + sm[tid];
        s = d * d;
    }
    red[tid] = s; __syncthreads();
    for (int off = 128; off > 0; off >>= 1) {
        if (tid < off) red[tid] += red[tid + off];
        __syncthreads();
    }
    if (tid == 0) partials[blockIdx.x] = red[0];
}

// ---------------- fused GEMM: 11-deep rolling af, 2-deep noise, cvt_pk packing --------------
__global__ __launch_bounds__(256, 3) void k_gemm(
        const float* __restrict__ noise, const float* __restrict__ F,
        const float* __restrict__ llev, const short* __restrict__ W1T,
        const float* __restrict__ b1, const short* __restrict__ W2T,
        const float* __restrict__ b2, const float* __restrict__ partials,
        const int* __restrict__ lvp, float* __restrict__ out,
        float* __restrict__ labels, float* __restrict__ loss) {
    __shared__ __align__(16) short hlds[64][360];   // 46080 B (cols 336..351 exact zeros)
    __shared__ __align__(16) float Flds[448];
    __shared__ __align__(16) float Llds[64];
    __shared__ __align__(16) float b1lds[352];      // total 49536 B -> 3 blocks/CU

    int t = threadIdx.x, w = t >> 6, l = t & 63;
    int lm = l & 15, lq = l >> 4;
    long n0 = (long)blockIdx.x * 64;

    // loss final (block 0, wave 3) — independent, no extra barriers
    if (blockIdx.x == 0 && w == 3) {
        float s = partials[l] + partials[l + 64] + partials[l + 128];
        if (l < 4) s += partials[l + 192];
#pragma unroll
        for (int off = 32; off > 0; off >>= 1) s += __shfl_down(s, off, 64);
        if (l == 0) loss[0] = s / (float)(T_LEN - 2) * (float)lvp[0];
    }

    // stage Flds / Llds / b1lds
    if (t < 112)      *(f32x4*)&Flds[t * 4] = *(const f32x4*)&F[n0 + t * 4];
    else if (t < 128) *(f32x4*)&Llds[(t - 112) * 4] = *(const f32x4*)&llev[n0 + W_IN + (t - 112) * 4];
    else if (t < 216) {
        int i4 = (t - 128) * 4;
        f32x4 v = (f32x4){0.f, 0.f, 0.f, 0.f};
        if (i4 < W_IN) v = *(const f32x4*)&b1[i4];
        *(f32x4*)&b1lds[i4] = v;
    }

    int rbase = (w >> 1) * 32;     // sample-row base (2 waves share j-halves)
    int jbase = (w & 1) * 176;     // j base
    long an0 = n0 + rbase + lm, an1 = an0 + 16;
    const long amax = (long)N_ROWS * W_IN - 8;
    long a00 = an0 * W_IN, a10 = an1 * W_IN;

    // noise prefetch, 2-deep: ncE = ks0, ncO = ks1
    f32x4 ncE00, ncE01, ncE10, ncE11, ncO00, ncO01, ncO10, ncO11;
    {
        long p0 = a00 + lq * 8; if (p0 > amax) p0 = amax;
        long p1 = a10 + lq * 8; if (p1 > amax) p1 = amax;
        ncE00 = *(const f32x4*)&noise[p0]; ncE01 = *(const f32x4*)&noise[p0 + 4];
        ncE10 = *(const f32x4*)&noise[p1]; ncE11 = *(const f32x4*)&noise[p1 + 4];
        long q0 = a00 + 32 + lq * 8; if (q0 > amax) q0 = amax;
        long q1 = a10 + 32 + lq * 8; if (q1 > amax) q1 = amax;
        ncO00 = *(const f32x4*)&noise[q0]; ncO01 = *(const f32x4*)&noise[q0 + 4];
        ncO10 = *(const f32x4*)&noise[q1]; ncO11 = *(const f32x4*)&noise[q1 + 4];
    }

    f32x4 acc0[11], acc1[11];
#pragma unroll
    for (int c = 0; c < 11; ++c) { acc0[c] = (f32x4){0,0,0,0}; acc1[c] = (f32x4){0,0,0,0}; }

    const short* w1row = &W1T[(jbase + lm) * 352 + lq * 8];
#define LDW(CT, KS) (*(const s16x8*)&w1row[(CT) * 5632 + (KS) * 32])
    // af rolling bank: loaded for ks=0; each reloaded for ks+1 right after its MFMA
    s16x8 af0 = LDW(0,0), af1 = LDW(1,0), af2 = LDW(2,0), af3 = LDW(3,0), af4 = LDW(4,0),
          af5 = LDW(5,0), af6 = LDW(6,0), af7 = LDW(7,0), af8 = LDW(8,0), af9 = LDW(9,0),
          af10 = LDW(10,0);

    __syncthreads();
    float lv0 = Llds[rbase + lm], lv1 = Llds[rbase + 16 + lm];

#define MM2(CT, AF) \
    acc0[CT] = __builtin_amdgcn_mfma_f32_16x16x32_bf16(AF, bf0, acc0[CT], 0, 0, 0); \
    acc1[CT] = __builtin_amdgcn_mfma_f32_16x16x32_bf16(AF, bf1, acc1[CT], 0, 0, 0);

#define KSTEP(KS, NCX) { \
    s16x8 bf0, bf1; \
    { int fb = rbase + lm + (KS) * 32 + lq * 8; \
      int* b0i = (int*)&bf0; int* b1i = (int*)&bf1; \
      b0i[0] = bfpk(Flds[fb+0]  - lv0 + NCX##00[0], Flds[fb+1]  - lv0 + NCX##00[1]); \
      b0i[1] = bfpk(Flds[fb+2]  - lv0 + NCX##00[2], Flds[fb+3]  - lv0 + NCX##00[3]); \
      b0i[2] = bfpk(Flds[fb+4]  - lv0 + NCX##01[0], Flds[fb+5]  - lv0 + NCX##01[1]); \
      b0i[3] = bfpk(Flds[fb+6]  - lv0 + NCX##01[2], Flds[fb+7]  - lv0 + NCX##01[3]); \
      b1i[0] = bfpk(Flds[fb+16] - lv1 + NCX##10[0], Flds[fb+17] - lv1 + NCX##10[1]); \
      b1i[1] = bfpk(Flds[fb+18] - lv1 + NCX##10[2], Flds[fb+19] - lv1 + NCX##10[3]); \
      b1i[2] = bfpk(Flds[fb+20] - lv1 + NCX##11[0], Flds[fb+21] - lv1 + NCX##11[1]); \
      b1i[3] = bfpk(Flds[fb+22] - lv1 + NCX##11[2], Flds[fb+23] - lv1 + NCX##11[3]); } \
    if ((KS) + 2 <= 10) { \
      int kb = ((KS) + 2) * 32 + lq * 8; \
      long q0 = a00 + kb; if (q0 > amax) q0 = amax; \
      long q1 = a10 + kb; if (q1 > amax) q1 = amax; \
      NCX##00 = *(const f32x4*)&noise[q0]; NCX##01 = *(const f32x4*)&noise[q0 + 4]; \
      NCX##10 = *(const f32x4*)&noise[q1]; NCX##11 = *(const f32x4*)&noise[q1 + 4]; \
    } \
    MM2(0, af0)   if ((KS) < 10) af0  = LDW(0,  (KS) + 1); \
    MM2(1, af1)   if ((KS) < 10) af1  = LDW(1,  (KS) + 1); \
    MM2(2, af2)   if ((KS) < 10) af2  = LDW(2,  (KS) + 1); \
    MM2(3, af3)   if ((KS) < 10) af3  = LDW(3,  (KS) + 1); \
    MM2(4, af4)   if ((KS) < 10) af4  = LDW(4,  (KS) + 1); \
    MM2(5, af5)   if ((KS) < 10) af5  = LDW(5,  (KS) + 1); \
    MM2(6, af6)   if ((KS) < 10) af6  = LDW(6,  (KS) + 1); \
    MM2(7, af7)   if ((KS) < 10) af7  = LDW(7,  (KS) + 1); \
    MM2(8, af8)   if ((KS) < 10) af8  = LDW(8,  (KS) + 1); \
    MM2(9, af9)   if ((KS) < 10) af9  = LDW(9,  (KS) + 1); \
    MM2(10, af10) if ((KS) < 10) af10 = LDW(10, (KS) + 1); \
}

    KSTEP(0, ncE) KSTEP(1, ncO) KSTEP(2, ncE) KSTEP(3, ncO) KSTEP(4, ncE)
    KSTEP(5, ncO) KSTEP(6, ncE) KSTEP(7, ncO) KSTEP(8, ncE) KSTEP(9, ncO)
    KSTEP(10, ncE)
#undef KSTEP
#undef MM2
#undef LDW

    // epilogue 1: bias + tanh -> hlds (stride 360; cols 336..351 exact zeros)
#pragma unroll
    for (int ct = 0; ct < 11; ++ct) {
        f32x4 b1q = *(f32x4*)&b1lds[jbase + ct * 16 + lq * 4];
        int2 p0, p1;
        p0.x = bfpk(fast_tanh(acc0[ct][0] + b1q[0]), fast_tanh(acc0[ct][1] + b1q[1]));
        p0.y = bfpk(fast_tanh(acc0[ct][2] + b1q[2]), fast_tanh(acc0[ct][3] + b1q[3]));
        p1.x = bfpk(fast_tanh(acc1[ct][0] + b1q[0]), fast_tanh(acc1[ct][1] + b1q[1]));
        p1.y = bfpk(fast_tanh(acc1[ct][2] + b1q[2]), fast_tanh(acc1[ct][3] + b1q[3]));
        *(int2*)&hlds[rbase + lm][jbase + ct * 16 + lq * 4]      = p0;
        *(int2*)&hlds[rbase + 16 + lm][jbase + ct * 16 + lq * 4] = p1;
    }
    __syncthreads();

    // gemm2: out-tile = h @ W2 (W2 fragments direct from global; L1/L2-hot)
    f32x4 a2[3];
    a2[0] = (f32x4){0,0,0,0}; a2[1] = (f32x4){0,0,0,0}; a2[2] = (f32x4){0,0,0,0};
#pragma unroll
    for (int ks = 0; ks < 11; ++ks) {
        s16x8 hf = *(s16x8*)&hlds[w * 16 + lm][ks * 32 + lq * 8];
#pragma unroll
        for (int ct = 0; ct < 3; ++ct) {
            s16x8 bf2 = *(const s16x8*)&W2T[(ct * 16 + lm) * 360 + ks * 32 + lq * 8];
            a2[ct] = __builtin_amdgcn_mfma_f32_16x16x32_bf16(hf, bf2, a2[ct], 0, 0, 0);
        }
    }

    // epilogue 2: out + labels (labels entirely from LDS)
    int rloc = w * 16 + lq * 4;
#pragma unroll
    for (int ct = 0; ct < 3; ++ct) {
        float b2v = b2[ct * 16 + lm];
#pragma unroll
        for (int r = 0; r < 4; ++r) {
            long row = n0 + rloc + r;
            if (row < N_ROWS) {
                int col = ct * 16 + lm;
                out[row * O_OUT + col]    = a2[ct][r] + b2v;
                labels[row * O_OUT + col] = Flds[rloc + r + W_IN + col] - Llds[rloc + r];
            }
        }
    }
}

extern "C" void kernel_launch(void* const* d_in, const int* in_sizes, int n_in,
                              void* d_out, int out_size, void* d_ws, size_t ws_size,
                              hipStream_t stream) {
    const float* x         = (const float*)d_in[0];
    const float* noise     = (const float*)d_in[1];
    const float* level_sc  = (const float*)d_in[2];
    const float* seas_sc   = (const float*)d_in[3];
    const float* init_seas = (const float*)d_in[4];
    const float* W1        = (const float*)d_in[5];
    const float* b1        = (const float*)d_in[6];
    const float* W2        = (const float*)d_in[7];
    const float* b2        = (const float*)d_in[8];
    const int*   lvp       = (const int*)d_in[11];

    float* out    = (float*)d_out;
    float* labels = out + (long)N_ROWS * O_OUT;
    float* loss   = labels + (long)N_ROWS * O_OUT;

    float* wsf      = (float*)d_ws;
    float* lw       = wsf;                 // 2*50000 packed {level,w} (reserve 100096)
    float* seasinit = wsf + 100096;        // 169 (reserve 192)
    float* F        = wsf + 100288;        // 50000 (reserve 50176; gemm reads to n0+447)
    float* llev     = wsf + 150464;        // 50000 (reserve 50048)
    float* partials = wsf + 200512;        // 196 (reserve 256)
    short* W1T      = (short*)(wsf + 200768);   // 352*352 bf16 (zero-padded)
    short* W2T      = W1T + 352 * 352;          // 48*360 bf16

    k_preconvert<<<552, 256, 0, stream>>>(W1, W2, W1T, W2T);
    k_scan<<<1, 64, 0, stream>>>(x, level_sc, seas_sc, init_seas, lw, seasinit);
    k_logs<<<196, 256, 0, stream>>>(x, lw, seasinit, F, llev, partials);
    k_gemm<<<NBLK, 256, 0, stream>>>(noise, F, llev, W1T, b1, W2T, b2,
                                     partials, lvp, out, labels, loss);
}

// Round 10
// 157.563 us; speedup vs baseline: 1.0492x; 1.0492x over previous
//
#include <hip/hip_runtime.h>
#include <hip/hip_bf16.h>

typedef __attribute__((ext_vector_type(8))) short  s16x8;   // 8 x bf16
typedef __attribute__((ext_vector_type(4))) short  s16x4;
typedef __attribute__((ext_vector_type(4))) float  f32x4;

#define T_LEN 50000
#define S_LEN 168
#define W_IN  336
#define O_OUT 48
#define N_ROWS (T_LEN - W_IN - O_OUT + 1)   // 49617
#define N_PAD  49664                        // 776 * 64
#define NBLK   (N_PAD / 64)                 // 776

__device__ inline short f2bf(float f) {
    union { float f; unsigned u; } v; v.f = f;
    unsigned u = v.u;
    unsigned r = u + 0x7fffu + ((u >> 16) & 1u);   // RNE
    return (short)(r >> 16);
}

__device__ inline int bfpk(float lo, float hi) {   // 2xf32 -> packed 2xbf16 (RNE)
    float2 f2; f2.x = lo; f2.y = hi;
    __hip_bfloat162 h = __float22bfloat162_rn(f2);
    int r; __builtin_memcpy(&r, &h, 4);
    return r;
}

__device__ inline float readlane_f(float v, int l) {
    return __int_as_float(__builtin_amdgcn_readlane(__float_as_int(v), l));
}

__device__ inline float fast_tanh(float v) {
    float e = __expf(2.f * v);
    return 1.f - 2.f * __builtin_amdgcn_rcpf(e + 1.f);
}

// ---- pre-convert W1 -> W1T bf16 [352][352], W2 -> W2T [48][360], S1[j] = colsum(W1) -------
__global__ void k_preconvert(const float* __restrict__ W1, const float* __restrict__ W2,
                             short* __restrict__ W1T, short* __restrict__ W2T,
                             float* __restrict__ S1) {
    int idx = blockIdx.x * 256 + threadIdx.x;
    const int n1 = 352 * 352;
    const int n2 = n1 + 48 * 360;
    if (idx < n1) {
        int j = idx / 352, k = idx % 352;
        W1T[idx] = (j < 336 && k < 336) ? f2bf(W1[k * 336 + j]) : (short)0;
    } else if (idx < n2) {
        int i2 = idx - n1;
        int o = i2 / 360, k = i2 % 360;
        W2T[i2] = (k < 336) ? f2bf(W2[k * 48 + o]) : (short)0;
    } else if (idx < n2 + 352) {
        int j = idx - n2;
        float s = 0.f;
        if (j < 336)
            for (int k = 0; k < 336; ++k) s += W1[k * 336 + j];
        S1[j] = s;
    }
}

// ---------------- scan: packed lw stores, row_bcast DPP scan, peeled clamp -----------------
#define DPP_FMA(q_, CTRL, W, RM) { \
    int t_ = __builtin_amdgcn_update_dpp(0, __float_as_int(q_), (CTRL), (RM), 0xf, true); \
    q_ = fmaf((W), __int_as_float(t_), q_); }

__global__ void k_scan(const float* __restrict__ x, const float* __restrict__ level_sc,
                       const float* __restrict__ seas_sc, const float* __restrict__ init_seas,
                       float* __restrict__ lw, float* __restrict__ seasinit) {
    __shared__ float ring[256];      // ring[s & 255] = seas(s)
    int lane = threadIdx.x;          // 64 threads, 1 wave
    float a = 1.f / (1.f + expf(-level_sc[0]));
    float g = 1.f / (1.f + expf(-seas_sc[0]));
    float om = 1.f - a, omg = 1.f - g;

    for (int t = lane; t < 256; t += 64) {
        float s = 1.f;
        if (t <= S_LEN) { s = expf(init_seas[t < S_LEN ? t : 0]); seasinit[t] = s; }
        ring[t] = s;
    }
    float lpv = x[0] / expf(init_seas[0]);
    if (lane == 0) { lw[0] = lpv; lw[1] = 1.f; }
    __syncthreads();

    float om1 = om, om2v = om1 * om1, om4 = om2v * om2v, om8 = om4 * om4;
    float pl    = powf(om, (float)(lane + 1));
    float fpre  = powf(om, (float)((lane & 15) + 1));
    float fpre2 = powf(om, (float)((lane & 31) + 1));

#define SCAN(QOUT, XV, RSV) { \
    float q_ = a * (XV) * (RSV); \
    DPP_FMA(q_, 0x111, om1,  0xf); \
    DPP_FMA(q_, 0x112, om2v, 0xf); \
    DPP_FMA(q_, 0x114, om4,  0xf); \
    DPP_FMA(q_, 0x118, om8,  0xf); \
    DPP_FMA(q_, 0x142, fpre,  0xa); \
    DPP_FMA(q_, 0x143, fpre2, 0xc); \
    QOUT = q_; }

#define XLOAD(I) float xr##I = x[1 + 64 * I + lane];
    XLOAD(0) XLOAD(1) XLOAD(2) XLOAD(3) XLOAD(4) XLOAD(5) XLOAD(6) XLOAD(7)
    XLOAD(8) XLOAD(9) XLOAD(10) XLOAD(11) XLOAD(12) XLOAD(13) XLOAD(14) XLOAD(15)
#undef XLOAD

    float sA0 = ring[1 + lane];
    float Qcur; SCAN(Qcur, xr0, __builtin_amdgcn_rcpf(sA0));
    float sW = sA0;
    float ldsA = ring[65 + lane];
    float ldsB;
    int ib = 1;

#define BODY(R, RN, LIN, LOUT, CLAMP) { \
    float lvl = fmaf(pl, lpv, Qcur); \
    lpv = readlane_f(lvl, 63); \
    float w_ = fmaf(omg, sW, (g * xr##R) * __builtin_amdgcn_rcpf(lvl)); \
    float2 pk_; pk_.x = lvl; pk_.y = w_; \
    *(float2*)&lw[2 * (ib + lane)] = pk_; \
    ring[(ib + S_LEN + lane) & 255] = w_; \
    LOUT = ring[(ib + 128 + lane) & 255]; \
    float Qn_; SCAN(Qn_, xr##RN, __builtin_amdgcn_rcpf(LIN)); \
    int pidx = ib + 1024 + lane; \
    if (CLAMP) pidx = pidx > (T_LEN - 1) ? (T_LEN - 1) : pidx; \
    xr##R = x[pidx]; \
    Qcur = Qn_; sW = LIN; \
    ib += 64; }

    for (int kb = 0; kb < 47; ++kb) {   // 47*16 = 752 unclamped iters
        BODY(0,1,  ldsA, ldsB, 0) BODY(1,2,  ldsB, ldsA, 0) BODY(2,3,  ldsA, ldsB, 0) BODY(3,4,  ldsB, ldsA, 0)
        BODY(4,5,  ldsA, ldsB, 0) BODY(5,6,  ldsB, ldsA, 0) BODY(6,7,  ldsA, ldsB, 0) BODY(7,8,  ldsB, ldsA, 0)
        BODY(8,9,  ldsA, ldsB, 0) BODY(9,10, ldsB, ldsA, 0) BODY(10,11,ldsA, ldsB, 0) BODY(11,12,ldsB, ldsA, 0)
        BODY(12,13,ldsA, ldsB, 0) BODY(13,14,ldsB, ldsA, 0) BODY(14,15,ldsA, ldsB, 0) BODY(15,0, ldsB, ldsA, 0)
    }
    // 13 unclamped: k = 752..764
    BODY(0,1,  ldsA, ldsB, 0) BODY(1,2,  ldsB, ldsA, 0) BODY(2,3,  ldsA, ldsB, 0) BODY(3,4,  ldsB, ldsA, 0)
    BODY(4,5,  ldsA, ldsB, 0) BODY(5,6,  ldsB, ldsA, 0) BODY(6,7,  ldsA, ldsB, 0) BODY(7,8,  ldsB, ldsA, 0)
    BODY(8,9,  ldsA, ldsB, 0) BODY(9,10, ldsB, ldsA, 0) BODY(10,11,ldsA, ldsB, 0) BODY(11,12,ldsB, ldsA, 0)
    BODY(12,13,ldsA, ldsB, 0)
    // 15 clamped: k = 765..779
    BODY(13,14,ldsB, ldsA, 1) BODY(14,15,ldsA, ldsB, 1) BODY(15,0, ldsB, ldsA, 1)
    BODY(0,1,  ldsA, ldsB, 1) BODY(1,2,  ldsB, ldsA, 1) BODY(2,3,  ldsA, ldsB, 1) BODY(3,4,  ldsB, ldsA, 1)
    BODY(4,5,  ldsA, ldsB, 1) BODY(5,6,  ldsB, ldsA, 1) BODY(6,7,  ldsA, ldsB, 1) BODY(7,8,  ldsB, ldsA, 1)
    BODY(8,9,  ldsA, ldsB, 1) BODY(9,10, ldsB, ldsA, 1) BODY(10,11,ldsA, ldsB, 1) BODY(11,12,ldsB, ldsA, 1)
#undef BODY

    {   // chunk 780
        float lvl = fmaf(pl, lpv, Qcur);
        lpv = readlane_f(lvl, 63);
        float w_ = fmaf(omg, sW, (g * xr12) * __builtin_amdgcn_rcpf(lvl));
        float2 pk_; pk_.x = lvl; pk_.y = w_;
        *(float2*)&lw[2 * (49921 + lane)] = pk_;
    }
    {   // chunk 781 (lanes 0..14)
        float Qn_; SCAN(Qn_, xr13, __builtin_amdgcn_rcpf(ldsA));
        float lvl = fmaf(pl, lpv, Qn_);
        if (lane < 15) {
            float w_ = fmaf(omg, ldsA, (g * xr13) * __builtin_amdgcn_rcpf(lvl));
            float2 pk_; pk_.x = lvl; pk_.y = w_;
            *(float2*)&lw[2 * (49985 + lane)] = pk_;
        }
    }
#undef SCAN
}

// ---------------- logs + loss partials: F, llev from packed lw ------------------------------
__global__ void k_logs(const float* __restrict__ x, const float* __restrict__ lw,
                       const float* __restrict__ seasinit,
                       float* __restrict__ F, float* __restrict__ llev,
                       float* __restrict__ partials) {
    __shared__ float sm[258];
    __shared__ float red[256];
    int tid = threadIdx.x;
    int t = blockIdx.x * 256 + tid;
    float ll = 0.f;
    if (t < T_LEN) {
        float2 cur = *(const float2*)&lw[2 * t];
        int ps = t - S_LEN; if (ps < 0) ps = 0;
        float sv = (t <= S_LEN) ? seasinit[t] : lw[2 * ps + 1];
        F[t]  = __logf(x[t]) - __logf(sv);
        ll    = __logf(cur.x);
        llev[t] = ll;
    }
    sm[tid] = ll;
    if (tid < 2) {
        int te = blockIdx.x * 256 + 256 + tid;
        sm[256 + tid] = (te < T_LEN) ? __logf(lw[2 * te]) : 0.f;
    }
    __syncthreads();
    float s = 0.f;
    if (t < T_LEN - 2) {
        float d = sm[tid + 2] - 2.f * sm[tid + 1] + sm[tid];
        s = d * d;
    }
    red[tid] = s; __syncthreads();
    for (int off = 128; off > 0; off >>= 1) {
        if (tid < off) red[tid] += red[tid + off];
        __syncthreads();
    }
    if (tid == 0) partials[blockIdx.x] = red[0];
}

// ------- fused GEMM: R7 pipeline + register diet (lv-fold via S1, one-time clamp) ----------
__global__ __launch_bounds__(256, 3) void k_gemm(
        const float* __restrict__ noise, const float* __restrict__ F,
        const float* __restrict__ llev, const short* __restrict__ W1T,
        const float* __restrict__ b1, const short* __restrict__ W2T,
        const float* __restrict__ b2, const float* __restrict__ S1,
        const float* __restrict__ partials, const int* __restrict__ lvp,
        float* __restrict__ out, float* __restrict__ labels, float* __restrict__ loss) {
    __shared__ __align__(16) short hlds[64][360];   // 46080 B (cols 336..351 exact zeros)
    __shared__ __align__(16) float Flds[448];
    __shared__ __align__(16) float Llds[64];
    __shared__ __align__(16) float b1lds[352];
    __shared__ __align__(16) float S1lds[352];      // total 50944 B -> 3 blocks/CU (LDS)

    int t = threadIdx.x, w = t >> 6, l = t & 63;
    int lm = l & 15, lq = l >> 4;
    long n0 = (long)blockIdx.x * 64;

    // loss final (block 0, wave 3)
    if (blockIdx.x == 0 && w == 3) {
        float s = partials[l] + partials[l + 64] + partials[l + 128];
        if (l < 4) s += partials[l + 192];
#pragma unroll
        for (int off = 32; off > 0; off >>= 1) s += __shfl_down(s, off, 64);
        if (l == 0) loss[0] = s / (float)(T_LEN - 2) * (float)lvp[0];
    }

    // stage Flds / Llds / b1lds / S1lds
    if (t < 112)      *(f32x4*)&Flds[t * 4] = *(const f32x4*)&F[n0 + t * 4];
    else if (t < 128) *(f32x4*)&Llds[(t - 112) * 4] = *(const f32x4*)&llev[n0 + W_IN + (t - 112) * 4];
    else if (t < 216) {
        int i4 = (t - 128) * 4;
        f32x4 v = (f32x4){0.f, 0.f, 0.f, 0.f};
        if (i4 < W_IN) v = *(const f32x4*)&b1[i4];
        *(f32x4*)&b1lds[i4] = v;
    } else if (t < 304 - 48) {
        // t in [216, 256): covers first 160 of S1
        int i4 = (t - 216) * 4;
        *(f32x4*)&S1lds[i4] = *(const f32x4*)&S1[i4];
    }
    // remaining S1 (elements 160..351) staged by threads 0..47 (second task)
    if (t < 48) *(f32x4*)&S1lds[160 + t * 4] = *(const f32x4*)&S1[160 + t * 4];

    int rbase = (w >> 1) * 32;     // sample-row base (2 waves share j-halves)
    int jbase = (w & 1) * 176;     // j base
    // one-time row clamp: rows >= N_ROWS-1 are pad rows (outputs discarded); clamping to
    // N_ROWS-2 keeps every ks read in-bounds (max off = 351 <= 336+... within buffer).
    long an0 = n0 + rbase + lm;      if (an0 > N_ROWS - 2) an0 = N_ROWS - 2;
    long an1 = n0 + rbase + 16 + lm; if (an1 > N_ROWS - 2) an1 = N_ROWS - 2;
    const float* nr0 = noise + an0 * W_IN + lq * 8;
    const float* nr1 = noise + an1 * W_IN + lq * 8;

    // noise prefetch ks=0 (1-deep)
    f32x4 nc00 = *(const f32x4*)&nr0[0], nc01 = *(const f32x4*)&nr0[4];
    f32x4 nc10 = *(const f32x4*)&nr1[0], nc11 = *(const f32x4*)&nr1[4];

    f32x4 acc0[11], acc1[11];
#pragma unroll
    for (int c = 0; c < 11; ++c) { acc0[c] = (f32x4){0,0,0,0}; acc1[c] = (f32x4){0,0,0,0}; }

    __syncthreads();

    // K-loop: no barriers; af 3-deep rolling; bf = F + noise (lv folded out via S1)
    const short* w1row = &W1T[(jbase + lm) * 352 + lq * 8];
#define LDW(CT, KS) (*(const s16x8*)&w1row[(CT) * 5632 + (KS) * 32])
#define MM2(CT, AF) \
    acc0[CT] = __builtin_amdgcn_mfma_f32_16x16x32_bf16(AF, bf0, acc0[CT], 0, 0, 0); \
    acc1[CT] = __builtin_amdgcn_mfma_f32_16x16x32_bf16(AF, bf1, acc1[CT], 0, 0, 0);

#define KSTEP(KS) { \
    s16x8 bf0, bf1; \
    { int fb = rbase + lm + (KS) * 32 + lq * 8; \
      int* b0i = (int*)&bf0; int* b1i = (int*)&bf1; \
      b0i[0] = bfpk(Flds[fb+0]  + nc00[0], Flds[fb+1]  + nc00[1]); \
      b0i[1] = bfpk(Flds[fb+2]  + nc00[2], Flds[fb+3]  + nc00[3]); \
      b0i[2] = bfpk(Flds[fb+4]  + nc01[0], Flds[fb+5]  + nc01[1]); \
      b0i[3] = bfpk(Flds[fb+6]  + nc01[2], Flds[fb+7]  + nc01[3]); \
      b1i[0] = bfpk(Flds[fb+16] + nc10[0], Flds[fb+17] + nc10[1]); \
      b1i[1] = bfpk(Flds[fb+18] + nc10[2], Flds[fb+19] + nc10[3]); \
      b1i[2] = bfpk(Flds[fb+20] + nc11[0], Flds[fb+21] + nc11[1]); \
      b1i[3] = bfpk(Flds[fb+22] + nc11[2], Flds[fb+23] + nc11[3]); } \
    if ((KS) < 10) { \
      nc00 = *(const f32x4*)&nr0[((KS)+1)*32]; nc01 = *(const f32x4*)&nr0[((KS)+1)*32+4]; \
      nc10 = *(const f32x4*)&nr1[((KS)+1)*32]; nc11 = *(const f32x4*)&nr1[((KS)+1)*32+4]; \
    } \
    s16x8 af0 = LDW(0,KS), af1 = LDW(1,KS), af2 = LDW(2,KS); \
    MM2(0, af0)  af0 = LDW(3,KS); \
    MM2(1, af1)  af1 = LDW(4,KS); \
    MM2(2, af2)  af2 = LDW(5,KS); \
    MM2(3, af0)  af0 = LDW(6,KS); \
    MM2(4, af1)  af1 = LDW(7,KS); \
    MM2(5, af2)  af2 = LDW(8,KS); \
    MM2(6, af0)  af0 = LDW(9,KS); \
    MM2(7, af1)  af1 = LDW(10,KS); \
    MM2(8, af2) \
    MM2(9, af0) \
    MM2(10, af1) \
}

    KSTEP(0) KSTEP(1) KSTEP(2) KSTEP(3) KSTEP(4) KSTEP(5)
    KSTEP(6) KSTEP(7) KSTEP(8) KSTEP(9) KSTEP(10)
#undef KSTEP
#undef MM2
#undef LDW

    // epilogue 1: h = tanh(acc + b1 - lv*S1) -> hlds
    float lv0 = Llds[rbase + lm], lv1 = Llds[rbase + 16 + lm];
#pragma unroll
    for (int ct = 0; ct < 11; ++ct) {
        f32x4 b1q = *(f32x4*)&b1lds[jbase + ct * 16 + lq * 4];
        f32x4 s1q = *(f32x4*)&S1lds[jbase + ct * 16 + lq * 4];
        int2 p0, p1;
        p0.x = bfpk(fast_tanh(fmaf(-lv0, s1q[0], acc0[ct][0] + b1q[0])),
                    fast_tanh(fmaf(-lv0, s1q[1], acc0[ct][1] + b1q[1])));
        p0.y = bfpk(fast_tanh(fmaf(-lv0, s1q[2], acc0[ct][2] + b1q[2])),
                    fast_tanh(fmaf(-lv0, s1q[3], acc0[ct][3] + b1q[3])));
        p1.x = bfpk(fast_tanh(fmaf(-lv1, s1q[0], acc1[ct][0] + b1q[0])),
                    fast_tanh(fmaf(-lv1, s1q[1], acc1[ct][1] + b1q[1])));
        p1.y = bfpk(fast_tanh(fmaf(-lv1, s1q[2], acc1[ct][2] + b1q[2])),
                    fast_tanh(fmaf(-lv1, s1q[3], acc1[ct][3] + b1q[3])));
        *(int2*)&hlds[rbase + lm][jbase + ct * 16 + lq * 4]      = p0;
        *(int2*)&hlds[rbase + 16 + lm][jbase + ct * 16 + lq * 4] = p1;
    }
    __syncthreads();

    // gemm2: out-tile = h @ W2 (W2 from global; shared by all blocks -> L2-hot)
    f32x4 a2[3];
    a2[0] = (f32x4){0,0,0,0}; a2[1] = (f32x4){0,0,0,0}; a2[2] = (f32x4){0,0,0,0};
#pragma unroll
    for (int ks = 0; ks < 11; ++ks) {
        s16x8 hf = *(s16x8*)&hlds[w * 16 + lm][ks * 32 + lq * 8];
#pragma unroll
        for (int ct = 0; ct < 3; ++ct) {
            s16x8 bf2 = *(const s16x8*)&W2T[(ct * 16 + lm) * 360 + ks * 32 + lq * 8];
            a2[ct] = __builtin_amdgcn_mfma_f32_16x16x32_bf16(hf, bf2, a2[ct], 0, 0, 0);
        }
    }

    // epilogue 2: out + labels
    int rloc = w * 16 + lq * 4;
#pragma unroll
    for (int ct = 0; ct < 3; ++ct) {
        float b2v = b2[ct * 16 + lm];
#pragma unroll
        for (int r = 0; r < 4; ++r) {
            long row = n0 + rloc + r;
            if (row < N_ROWS) {
                int col = ct * 16 + lm;
                out[row * O_OUT + col]    = a2[ct][r] + b2v;
                labels[row * O_OUT + col] = Flds[rloc + r + W_IN + col] - Llds[rloc + r];
            }
        }
    }
}

extern "C" void kernel_launch(void* const* d_in, const int* in_sizes, int n_in,
                              void* d_out, int out_size, void* d_ws, size_t ws_size,
                              hipStream_t stream) {
    const float* x         = (const float*)d_in[0];
    const float* noise     = (const float*)d_in[1];
    const float* level_sc  = (const float*)d_in[2];
    const float* seas_sc   = (const float*)d_in[3];
    const float* init_seas = (const float*)d_in[4];
    const float* W1        = (const float*)d_in[5];
    const float* b1        = (const float*)d_in[6];
    const float* W2        = (const float*)d_in[7];
    const float* b2        = (const float*)d_in[8];
    const int*   lvp       = (const int*)d_in[11];

    float* out    = (float*)d_out;
    float* labels = out + (long)N_ROWS * O_OUT;
    float* loss   = labels + (long)N_ROWS * O_OUT;

    float* wsf      = (float*)d_ws;
    float* lw       = wsf;                 // 2*50000 packed {level,w} (reserve 100096)
    float* seasinit = wsf + 100096;        // 169 (reserve 192)
    float* F        = wsf + 100288;        // 50000 (reserve 50176)
    float* llev     = wsf + 150464;        // 50000 (reserve 50048)
    float* partials = wsf + 200512;        // 196 (reserve 256)
    float* S1f      = wsf + 200768;        // 352 (reserve 384)
    short* W1T      = (short*)(wsf + 201152);   // 352*352 bf16 (zero-padded)
    short* W2T      = W1T + 352 * 352;          // 48*360 bf16

    k_preconvert<<<554, 256, 0, stream>>>(W1, W2, W1T, W2T, S1f);
    k_scan<<<1, 64, 0, stream>>>(x, level_sc, seas_sc, init_seas, lw, seasinit);
    k_logs<<<196, 256, 0, stream>>>(x, lw, seasinit, F, llev, partials);
    k_gemm<<<NBLK, 256, 0, stream>>>(noise, F, llev, W1T, b1, W2T, b2, S1f,
                                     partials, lvp, out, labels, loss);
}